// Round 1
// 636.620 us; speedup vs baseline: 1.0288x; 1.0288x over previous
//
#include <hip/hip_runtime.h>

#define IH 480
#define IW 640
#define NB 8
#define OC 64
#define KK 5
#define PD 2
#define PX 4                 // pixels per thread along W
#define WT (IW / PX)         // 160 thread-columns per row

typedef float vfloat4 __attribute__((ext_vector_type(4)));

__global__ __launch_bounds__(256) void ndconv_kernel(
    const float* __restrict__ x,      // [8,1,480,640]
    const float* __restrict__ wgt,    // [1,64,5,5] -> flat [64,25]
    float* __restrict__ out)          // [8,64,480,640]
{
    int t = blockIdx.x * blockDim.x + threadIdx.x;   // over B*H*(W/PX)
    if (t >= NB * IH * WT) return;
    int wt = t % WT;
    int r  = t / WT;
    int h  = r % IH;
    int b  = r / IH;
    int w0 = wt * PX;

    const float* xb = x + (size_t)b * (IH * IW);

    // ---- column validity + clamped column index (shared across all 5 rows) ----
    int   ccol[PX + KK - 1];
    bool  cok [PX + KK - 1];
#pragma unroll
    for (int j = 0; j < PX + KK - 1; ++j) {
        int c = w0 - PD + j;
        cok[j]  = (unsigned)c < (unsigned)IW;
        ccol[j] = min(max(c, 0), IW - 1);
    }

    // ---- branchless 5x8 window load: clamped address + cndmask to 0 ----
    float v[KK][PX + KK - 1];
#pragma unroll
    for (int kh = 0; kh < KK; ++kh) {
        int hh  = h + kh - PD;
        bool hv = (unsigned)hh < (unsigned)IH;
        const float* xr = xb + min(max(hh, 0), IH - 1) * IW;
#pragma unroll
        for (int j = 0; j < PX + KK - 1; ++j) {
            float val = xr[ccol[j]];                 // always in-bounds, no branch
            v[kh][j]  = (hv && cok[j]) ? val : 0.0f; // exact 0 for padding
        }
    }

    // ---- per-pixel sum / valid-count, same accumulation order as baseline ----
    float sum[PX] = {0.f, 0.f, 0.f, 0.f};
    float cnt[PX] = {0.f, 0.f, 0.f, 0.f};
#pragma unroll
    for (int kh = 0; kh < KK; ++kh)
#pragma unroll
        for (int kw = 0; kw < KK; ++kw)
#pragma unroll
            for (int px = 0; px < PX; ++px) {
                float val = v[kh][kw + px];
                sum[px] += val;
                cnt[px] += (val > 1e-4f) ? 1.0f : 0.0f;
            }

    float mean[PX];
#pragma unroll
    for (int px = 0; px < PX; ++px)
        mean[px] = sum[px] / (cnt[px] + 1e-6f);      // exact div, matches baseline

    // ---- normalized patches, q[k][px] = (mean-v)*mask, k-major like baseline ----
    vfloat4 q[KK * KK];
#pragma unroll
    for (int kh = 0; kh < KK; ++kh)
#pragma unroll
        for (int kw = 0; kw < KK; ++kw) {
            int k = kh * KK + kw;
#pragma unroll
            for (int px = 0; px < PX; ++px) {
                float val = v[kh][kw + px];
                q[k][px] = (val > 1e-4f) ? (mean[px] - val) : 0.0f;
            }
        }

    float* ob = out + (size_t)b * OC * (IH * IW) + (size_t)h * IW + w0;

    // ---- 64 channels: scalar weight (SGPR) feeds 4 FMAs; float4 streaming store ----
#pragma unroll 2
    for (int o = 0; o < OC; ++o) {
        const float* wo = wgt + o * (KK * KK);       // wave-uniform -> s_load
        vfloat4 acc = (vfloat4)0.0f;
#pragma unroll
        for (int k = 0; k < KK * KK; ++k) {
            float wk = wo[k];
            acc[0] = fmaf(wk, q[k][0], acc[0]);
            acc[1] = fmaf(wk, q[k][1], acc[1]);
            acc[2] = fmaf(wk, q[k][2], acc[2]);
            acc[3] = fmaf(wk, q[k][3], acc[3]);
        }
        __builtin_nontemporal_store(
            acc, reinterpret_cast<vfloat4*>(ob + (size_t)o * (IH * IW)));
    }
}

extern "C" void kernel_launch(void* const* d_in, const int* in_sizes, int n_in,
                              void* d_out, int out_size, void* d_ws, size_t ws_size,
                              hipStream_t stream) {
    const float* x   = (const float*)d_in[0];
    const float* wgt = (const float*)d_in[1];
    float* out = (float*)d_out;

    const int total = NB * IH * WT;                  // 614,400 threads (4 px each)
    const int block = 256;
    const int grid  = (total + block - 1) / block;   // 2400 blocks
    ndconv_kernel<<<grid, block, 0, stream>>>(x, wgt, out);
}